// Round 4
// baseline (547.222 us; speedup 1.0000x reference)
//
#include <hip/hip_runtime.h>
#include <hip/hip_bf16.h>
#include <stdint.h>

// MMoE: E=16 experts, T=4 tasks, H=512, I=1024, B=8192.
// out[t,b] = sum_e g[b,t,e] * (sum_h relu(x@We^T+be)[b,e,h] * Wf[t,h]) + bf[t]
// R3 finding: error ~1.2e-2 is dtype-INsensitive (bf16 1.12e-2, fp16 1.87e-2,
// split-bf16 2^-17 1.22e-2) -> structural bug, magnitude points at the old
// LDS-transpose epilogue. R4: independent register-space epilogue (shfl
// butterfly over m16 lanes), deterministic 2-stage output (no atomics).
// GEMM core (m97 structure) + split-bf16 3-product precision kept.

#define E_ 16
#define T_ 4
#define H_ 512
#define I_ 1024
#define B_ 8192
#define N_ (E_ * H_) /* 8192 */
#define K_ I_        /* 1024 */

typedef __bf16 bf16x8 __attribute__((ext_vector_type(8)));
typedef float f32x4 __attribute__((ext_vector_type(4)));

__device__ __forceinline__ unsigned short f2bf_rne(float f) {
  unsigned int b = __float_as_uint(f);
  b += 0x7fffu + ((b >> 16) & 1u);
  return (unsigned short)(b >> 16);
}
__device__ __forceinline__ float bf2f(unsigned short h) {
  return __uint_as_float(((unsigned int)h) << 16);
}

// fp32 -> (bf16 hi, bf16 lo) split; lo = rne(v - float(hi))
__global__ __launch_bounds__(256) void cvt_split_kernel(const float* __restrict__ in,
                                                        unsigned short* __restrict__ hi,
                                                        unsigned short* __restrict__ lo,
                                                        int n4) {
  int i = blockIdx.x * 256 + threadIdx.x;
  if (i >= n4) return;
  float4 v = reinterpret_cast<const float4*>(in)[i];
  ushort4 h, l;
  h.x = f2bf_rne(v.x); l.x = f2bf_rne(v.x - bf2f(h.x));
  h.y = f2bf_rne(v.y); l.y = f2bf_rne(v.y - bf2f(h.y));
  h.z = f2bf_rne(v.z); l.z = f2bf_rne(v.z - bf2f(h.z));
  h.w = f2bf_rne(v.w); l.w = f2bf_rne(v.w - bf2f(h.w));
  reinterpret_cast<ushort4*>(hi)[i] = h;
  reinterpret_cast<ushort4*>(lo)[i] = l;
}

// gates: g[b,t,e] = softmax_e( x[b,:]@Wg[t,e,:] + bg[t,e] ), fp32.
__global__ __launch_bounds__(256) void gates_kernel(const float* __restrict__ x,
                                                    const float* __restrict__ Wg,
                                                    const float* __restrict__ bg,
                                                    float* __restrict__ g) {
  __shared__ float xs[16 * I_];  // 64 KB
  const int tid = threadIdx.x;
  const int b0 = blockIdx.x * 16;
  const float4* xg = reinterpret_cast<const float4*>(x + (size_t)b0 * I_);
  float4* xs4 = reinterpret_cast<float4*>(xs);
#pragma unroll
  for (int it = 0; it < 16; ++it) xs4[tid + 256 * it] = xg[tid + 256 * it];
  __syncthreads();

  const int te = tid & 63;    // t = te>>4, e = te&15
  const int bgrp = tid >> 6;  // wave id -> which 4 b-rows
  const float4* wg4 = reinterpret_cast<const float4*>(Wg + (size_t)te * I_);
  float acc[4] = {0.f, 0.f, 0.f, 0.f};
  for (int i4 = 0; i4 < I_ / 4; ++i4) {
    float4 wv = wg4[i4];
#pragma unroll
    for (int bl = 0; bl < 4; ++bl) {
      float4 xv = xs4[(bgrp * 4 + bl) * (I_ / 4) + i4];  // wave-uniform: LDS broadcast
      acc[bl] += wv.x * xv.x + wv.y * xv.y + wv.z * xv.z + wv.w * xv.w;
    }
  }
  float bgv = bg[te];
#pragma unroll
  for (int bl = 0; bl < 4; ++bl) {
    float logit = acc[bl] + bgv;
    float m = logit;
#pragma unroll
    for (int mask = 1; mask < 16; mask <<= 1) m = fmaxf(m, __shfl_xor(m, mask, 64));
    float ex = __expf(logit - m);
    float s = ex;
#pragma unroll
    for (int mask = 1; mask < 16; mask <<= 1) s += __shfl_xor(s, mask, 64);
    int b = b0 + bgrp * 4 + bl;
    g[(size_t)b * 64 + te] = ex / s;
  }
}

__device__ __forceinline__ void gld_lds16(const void* gp, void* lp) {
  __builtin_amdgcn_global_load_lds((const __attribute__((address_space(1))) void*)gp,
                                   (__attribute__((address_space(3))) void*)lp, 16, 0, 0);
}

// Main: split-bf16 GEMM C = Ah*Bh + Ah*Bl + Al*Bh (fp32 acc), relu+bias,
// Wf-contraction + gating in REGISTERS (shfl butterfly), per-tile partial
// to global partials[nb][t][b] (deterministic; no atomics).
__global__ __launch_bounds__(256, 2) void moe_main_kernel(
    const unsigned short* __restrict__ Ah,  // x bf16-hi [B_][K_]
    const unsigned short* __restrict__ Al,  // x bf16-lo
    const unsigned short* __restrict__ Bh,  // We bf16-hi [N_][K_]
    const unsigned short* __restrict__ Bl,  // We bf16-lo
    const float* __restrict__ be,           // [E_*H_] flat == indexed by n
    const float* __restrict__ Wf,           // [T_][H_]
    const float* __restrict__ g,            // [B_][64] (t*16+e)
    float* __restrict__ partials)           // [64 nb][T_][B_]
{
  __shared__ struct {
    unsigned short Ah[128 * 32];
    unsigned short Al[128 * 32];
    unsigned short Bh[128 * 32];
    unsigned short Bl[128 * 32];
  } st;                                // 32 KB staging
  __shared__ float allsums[2 * 512];   // [wn][row*4+t], 4 KB

  const int tid = threadIdx.x;
  const int w = tid >> 6, l = tid & 63;
  const int wm = w >> 1, wn = w & 1;
  const int m16 = l & 15, q = l >> 4;
  const int nb = blockIdx.x, mb = blockIdx.y;
  const size_t m0 = (size_t)mb * 128, n0 = (size_t)nb * 128;

  // staging: LDS row-major [128][4 chunks of 16B]; chunk c of row r at slot c^((r>>1)&3)
  const int r0s = (w * 2 + 0) * 16 + (l >> 2);
  const int r1s = (w * 2 + 1) * 16 + (l >> 2);
  const int slot = l & 3;
  const int c0 = slot ^ ((r0s >> 1) & 3);
  const int c1 = slot ^ ((r1s >> 1) & 3);
  const size_t offA0 = (m0 + r0s) * K_ + c0 * 8;
  const size_t offA1 = (m0 + r1s) * K_ + c1 * 8;
  const size_t offB0 = (n0 + r0s) * K_ + c0 * 8;
  const size_t offB1 = (n0 + r1s) * K_ + c1 * 8;
  const int l0 = (w * 2 + 0) * 512;  // wave-uniform LDS base (HW adds lane*16)
  const int l1 = (w * 2 + 1) * 512;

  const int arow = wm * 64 + m16;
  const int brow = wn * 64 + m16;
  const int sA = q ^ ((arow >> 1) & 3);  // constant over i: (i*16)>>1 ≡ 0 mod 4
  const int sB = q ^ ((brow >> 1) & 3);

  f32x4 acc[4][4] = {};

  for (int k0 = 0; k0 < K_; k0 += 32) {
    __syncthreads();
    gld_lds16(Ah + offA0 + k0, st.Ah + l0);
    gld_lds16(Ah + offA1 + k0, st.Ah + l1);
    gld_lds16(Al + offA0 + k0, st.Al + l0);
    gld_lds16(Al + offA1 + k0, st.Al + l1);
    gld_lds16(Bh + offB0 + k0, st.Bh + l0);
    gld_lds16(Bh + offB1 + k0, st.Bh + l1);
    gld_lds16(Bl + offB0 + k0, st.Bl + l0);
    gld_lds16(Bl + offB1 + k0, st.Bl + l1);
    __syncthreads();  // vmcnt(0) drain before barrier
    bf16x8 ah[4], al[4], bh[4], bl[4];
#pragma unroll
    for (int i = 0; i < 4; ++i) {
      int o = (arow + i * 16) * 32 + sA * 8;
      ah[i] = *reinterpret_cast<const bf16x8*>(st.Ah + o);
      al[i] = *reinterpret_cast<const bf16x8*>(st.Al + o);
    }
#pragma unroll
    for (int j = 0; j < 4; ++j) {
      int o = (brow + j * 16) * 32 + sB * 8;
      bh[j] = *reinterpret_cast<const bf16x8*>(st.Bh + o);
      bl[j] = *reinterpret_cast<const bf16x8*>(st.Bl + o);
    }
#pragma unroll
    for (int i = 0; i < 4; ++i)
#pragma unroll
      for (int j = 0; j < 4; ++j) {
        acc[i][j] = __builtin_amdgcn_mfma_f32_16x16x32_bf16(ah[i], bh[j], acc[i][j], 0, 0, 0);
        acc[i][j] = __builtin_amdgcn_mfma_f32_16x16x32_bf16(ah[i], bl[j], acc[i][j], 0, 0, 0);
        acc[i][j] = __builtin_amdgcn_mfma_f32_16x16x32_bf16(al[i], bh[j], acc[i][j], 0, 0, 0);
      }
  }

  __syncthreads();

  const int hbase = (int)(n0 & 511);  // h-offset of this tile (expert = n0>>9)

  // Per-lane epilogue: this lane's acc element (i,j,reg) is
  // D[row = wm*64+16i+4q+reg][col = wn*64+16j+m16]  (C/D: col=lane&15, row=4*(lane>>4)+reg)
  float wfv[4][4];  // [t][j] = Wf[t][hbase + col(j)]
#pragma unroll
  for (int t = 0; t < 4; ++t)
#pragma unroll
    for (int j = 0; j < 4; ++j)
      wfv[t][j] = Wf[t * H_ + hbase + wn * 64 + j * 16 + m16];
  float bias[4];
#pragma unroll
  for (int j = 0; j < 4; ++j) bias[j] = be[n0 + wn * 64 + j * 16 + m16];

  const int reg_sel = m16 >> 2, t_sel = m16 & 3;  // slot this lane owns after reduce
#pragma unroll
  for (int i = 0; i < 4; ++i) {
    float eo[4][4];  // [j][reg]
#pragma unroll
    for (int j = 0; j < 4; ++j)
#pragma unroll
      for (int r = 0; r < 4; ++r) eo[j][r] = fmaxf(acc[i][j][r] + bias[j], 0.f);
    float p[16];  // [reg*4 + t] partial over this lane's 4 cols
#pragma unroll
    for (int r = 0; r < 4; ++r)
#pragma unroll
      for (int t = 0; t < 4; ++t) {
        float v = 0.f;
#pragma unroll
        for (int j = 0; j < 4; ++j) v += eo[j][r] * wfv[t][j];
        p[r * 4 + t] = v;
      }
    // butterfly-sum over the 16 m16-lanes (same q => same rows, disjoint cols)
#pragma unroll
    for (int mask = 1; mask < 16; mask <<= 1)
#pragma unroll
      for (int s = 0; s < 16; ++s) p[s] += __shfl_xor(p[s], mask, 64);
    // lane keeps slot s = m16
    float v = p[0];
#pragma unroll
    for (int s = 1; s < 16; ++s) v = (m16 == s) ? p[s] : v;
    int row = wm * 64 + i * 16 + q * 4 + reg_sel;
    allsums[wn * 512 + row * 4 + t_sel] = v;
  }
  __syncthreads();

  // combine wn-halves, apply gate, emit per-tile partial (deterministic)
  const int e_idx = (int)(n0 >> 9);
#pragma unroll
  for (int oi = 0; oi < 2; ++oi) {
    int o = tid * 2 + oi;  // 512 = 128 rows x 4 t
    int row = o >> 2, t = o & 3;
    float s = allsums[row * 4 + t] + allsums[512 + row * 4 + t];
    size_t b = m0 + row;
    float gv = g[b * 64 + t * 16 + e_idx];
    partials[(size_t)nb * (T_ * B_) + (size_t)t * B_ + b] = gv * s;
  }
}

// out[t,b] = bf[t] + sum_nb partials[nb][t][b]
__global__ __launch_bounds__(256) void reduce_kernel(const float* __restrict__ partials,
                                                     const float* __restrict__ bfv,
                                                     float* __restrict__ out) {
  int i = blockIdx.x * 256 + threadIdx.x;  // T_*B_ = 32768
  float s = bfv[i >> 13];
#pragma unroll 4
  for (int nb = 0; nb < 64; ++nb) s += partials[(size_t)nb * (T_ * B_) + i];
  out[i] = s;
}

extern "C" void kernel_launch(void* const* d_in, const int* in_sizes, int n_in,
                              void* d_out, int out_size, void* d_ws, size_t ws_size,
                              hipStream_t stream) {
  const float* x = (const float*)d_in[0];   // [B, I]
  const float* We = (const float*)d_in[1];  // [E, H, I]
  const float* be = (const float*)d_in[2];  // [E, H]
  const float* Wg = (const float*)d_in[3];  // [T, E, I]
  const float* bg = (const float*)d_in[4];  // [T, E]
  const float* Wf = (const float*)d_in[5];  // [T, H]
  const float* bf = (const float*)d_in[6];  // [T]
  float* out = (float*)d_out;               // [T, B, 1]

  // ws: xh|xl|wh|wl (16.8MB each) | g (2.1MB) | partials (8.4MB) ~ 78MB
  unsigned short* xh = (unsigned short*)d_ws;
  unsigned short* xl = xh + (size_t)B_ * K_;
  unsigned short* wh = xl + (size_t)B_ * K_;
  unsigned short* wl = wh + (size_t)N_ * K_;
  float* g = (float*)(wl + (size_t)N_ * K_);
  float* partials = g + (size_t)B_ * 64;

  cvt_split_kernel<<<(B_ * K_ / 4 + 255) / 256, 256, 0, stream>>>(x, xh, xl, B_ * K_ / 4);
  cvt_split_kernel<<<(N_ * K_ / 4 + 255) / 256, 256, 0, stream>>>(We, wh, wl, N_ * K_ / 4);
  gates_kernel<<<B_ / 16, 256, 0, stream>>>(x, Wg, bg, g);
  dim3 grid(N_ / 128, B_ / 128);
  moe_main_kernel<<<grid, 256, 0, stream>>>(xh, xl, wh, wl, be, Wf, g, partials);
  reduce_kernel<<<(T_ * B_) / 256, 256, 0, stream>>>(partials, bf, out);
}

// Round 5
// 363.609 us; speedup vs baseline: 1.5050x; 1.5050x over previous
//
#include <hip/hip_runtime.h>
#include <hip/hip_bf16.h>
#include <stdint.h>

// MMoE: E=16 experts, T=4 tasks, H=512, I=1024, B=8192.
// out[t,b] = sum_e g[b,t,e] * (sum_h relu(x@We^T+be)[b,e,h] * Wf[t,h]) + bf[t]
// R4 finding: the old LDS-transpose epilogue was the bug (R1-R3 failures were
// NOT quantization). With the register/butterfly epilogue, split-bf16 passed at
// 9.77e-4. R5: drop the 3-product split -> single bf16 (predicted absmax
// ~1.5e-3 < 6.8e-3), main kernel MFMA work /3; fuse x->bf16 cvt into gates.

#define E_ 16
#define T_ 4
#define H_ 512
#define I_ 1024
#define B_ 8192
#define N_ (E_ * H_) /* 8192 */
#define K_ I_        /* 1024 */

typedef __bf16 bf16x8 __attribute__((ext_vector_type(8)));
typedef float f32x4 __attribute__((ext_vector_type(4)));

__device__ __forceinline__ unsigned short f2bf_rne(float f) {
  unsigned int b = __float_as_uint(f);
  b += 0x7fffu + ((b >> 16) & 1u);
  return (unsigned short)(b >> 16);
}

// fp32 -> bf16 (RNE), float4 in / ushort4 out per thread
__global__ __launch_bounds__(256) void cvt_bf16_kernel(const float* __restrict__ in,
                                                       unsigned short* __restrict__ out,
                                                       int n4) {
  int i = blockIdx.x * 256 + threadIdx.x;
  if (i >= n4) return;
  float4 v = reinterpret_cast<const float4*>(in)[i];
  ushort4 o;
  o.x = f2bf_rne(v.x);
  o.y = f2bf_rne(v.y);
  o.z = f2bf_rne(v.z);
  o.w = f2bf_rne(v.w);
  reinterpret_cast<ushort4*>(out)[i] = o;
}

// gates: g[b,t,e] = softmax_e( x[b,:]@Wg[t,e,:] + bg[t,e] ), fp32.
// Also emits x converted to bf16 (x tile already staged in LDS -> free read).
__global__ __launch_bounds__(256) void gates_kernel(const float* __restrict__ x,
                                                    const float* __restrict__ Wg,
                                                    const float* __restrict__ bg,
                                                    float* __restrict__ g,
                                                    unsigned short* __restrict__ xb) {
  __shared__ float xs[16 * I_];  // 64 KB
  const int tid = threadIdx.x;
  const int b0 = blockIdx.x * 16;
  const float4* xg = reinterpret_cast<const float4*>(x + (size_t)b0 * I_);
  float4* xs4 = reinterpret_cast<float4*>(xs);
#pragma unroll
  for (int it = 0; it < 16; ++it) xs4[tid + 256 * it] = xg[tid + 256 * it];
  __syncthreads();

  // fused x -> bf16 conversion (16 float4 per thread)
  ushort4* xb4 = reinterpret_cast<ushort4*>(xb + (size_t)b0 * I_);
#pragma unroll
  for (int it = 0; it < 16; ++it) {
    float4 v = xs4[tid + 256 * it];
    ushort4 o;
    o.x = f2bf_rne(v.x);
    o.y = f2bf_rne(v.y);
    o.z = f2bf_rne(v.z);
    o.w = f2bf_rne(v.w);
    xb4[tid + 256 * it] = o;
  }

  const int te = tid & 63;    // t = te>>4, e = te&15
  const int bgrp = tid >> 6;  // wave id -> which 4 b-rows
  const float4* wg4 = reinterpret_cast<const float4*>(Wg + (size_t)te * I_);
  float acc[4] = {0.f, 0.f, 0.f, 0.f};
  for (int i4 = 0; i4 < I_ / 4; ++i4) {
    float4 wv = wg4[i4];
#pragma unroll
    for (int bl = 0; bl < 4; ++bl) {
      float4 xv = xs4[(bgrp * 4 + bl) * (I_ / 4) + i4];  // wave-uniform: LDS broadcast
      acc[bl] += wv.x * xv.x + wv.y * xv.y + wv.z * xv.z + wv.w * xv.w;
    }
  }
  float bgv = bg[te];
#pragma unroll
  for (int bl = 0; bl < 4; ++bl) {
    float logit = acc[bl] + bgv;
    float m = logit;
#pragma unroll
    for (int mask = 1; mask < 16; mask <<= 1) m = fmaxf(m, __shfl_xor(m, mask, 64));
    float ex = __expf(logit - m);
    float s = ex;
#pragma unroll
    for (int mask = 1; mask < 16; mask <<= 1) s += __shfl_xor(s, mask, 64);
    int b = b0 + bgrp * 4 + bl;
    g[(size_t)b * 64 + te] = ex / s;
  }
}

__device__ __forceinline__ void gld_lds16(const void* gp, void* lp) {
  __builtin_amdgcn_global_load_lds((const __attribute__((address_space(1))) void*)gp,
                                   (__attribute__((address_space(3))) void*)lp, 16, 0, 0);
}

// Main: bf16 GEMM C = A x B^T (fp32 acc), relu+bias, Wf-contraction + gating
// in registers (shfl butterfly over the 16 m16-lanes), per-tile partial to
// global partials[nb][t][b] (deterministic; no atomics).
// m97 structure: 128x128 tile, BK=32, 4 waves x 4x4 of 16x16x32 MFMA,
// global_load_lds width=16 staging, XOR chunk swizzle for ds_read_b128.
__global__ __launch_bounds__(256, 2) void moe_main_kernel(
    const unsigned short* __restrict__ A,   // x bf16 [B_][K_]
    const unsigned short* __restrict__ Bm,  // We bf16 [N_][K_]
    const float* __restrict__ be,           // [E_*H_] flat == indexed by n
    const float* __restrict__ Wf,           // [T_][H_]
    const float* __restrict__ g,            // [B_][64] (t*16+e)
    float* __restrict__ partials)           // [64 nb][T_][B_]
{
  __shared__ struct {
    unsigned short A[128 * 32];
    unsigned short B[128 * 32];
  } st;                               // 16 KB staging
  __shared__ float allsums[2 * 512];  // [wn][row*4+t], 4 KB

  const int tid = threadIdx.x;
  const int w = tid >> 6, l = tid & 63;
  const int wm = w >> 1, wn = w & 1;
  const int m16 = l & 15, q = l >> 4;
  const int nb = blockIdx.x, mb = blockIdx.y;
  const size_t m0 = (size_t)mb * 128, n0 = (size_t)nb * 128;

  // staging: LDS row-major [128][4 chunks of 16B]; chunk c of row r at slot c^((r>>1)&3)
  const int r0s = (w * 2 + 0) * 16 + (l >> 2);
  const int r1s = (w * 2 + 1) * 16 + (l >> 2);
  const int slot = l & 3;
  const int c0 = slot ^ ((r0s >> 1) & 3);
  const int c1 = slot ^ ((r1s >> 1) & 3);
  const size_t offA0 = (m0 + r0s) * K_ + c0 * 8;
  const size_t offA1 = (m0 + r1s) * K_ + c1 * 8;
  const size_t offB0 = (n0 + r0s) * K_ + c0 * 8;
  const size_t offB1 = (n0 + r1s) * K_ + c1 * 8;
  const int l0 = (w * 2 + 0) * 512;  // wave-uniform LDS base (HW adds lane*16)
  const int l1 = (w * 2 + 1) * 512;

  const int arow = wm * 64 + m16;
  const int brow = wn * 64 + m16;
  const int sA = q ^ ((arow >> 1) & 3);  // constant over i: (i*16)>>1 ≡ 0 mod 4
  const int sB = q ^ ((brow >> 1) & 3);

  f32x4 acc[4][4] = {};

  for (int k0 = 0; k0 < K_; k0 += 32) {
    __syncthreads();
    gld_lds16(A + offA0 + k0, st.A + l0);
    gld_lds16(A + offA1 + k0, st.A + l1);
    gld_lds16(Bm + offB0 + k0, st.B + l0);
    gld_lds16(Bm + offB1 + k0, st.B + l1);
    __syncthreads();  // vmcnt(0) drain before barrier
    bf16x8 af[4], bfr[4];
#pragma unroll
    for (int i = 0; i < 4; ++i)
      af[i] = *reinterpret_cast<const bf16x8*>(st.A + (arow + i * 16) * 32 + sA * 8);
#pragma unroll
    for (int j = 0; j < 4; ++j)
      bfr[j] = *reinterpret_cast<const bf16x8*>(st.B + (brow + j * 16) * 32 + sB * 8);
#pragma unroll
    for (int i = 0; i < 4; ++i)
#pragma unroll
      for (int j = 0; j < 4; ++j)
        acc[i][j] = __builtin_amdgcn_mfma_f32_16x16x32_bf16(af[i], bfr[j], acc[i][j], 0, 0, 0);
  }

  __syncthreads();

  const int hbase = (int)(n0 & 511);  // h-offset of this tile (expert = n0>>9)

  // Per-lane epilogue: lane's acc element (i,j,reg) is
  // D[row = wm*64+16i+4q+reg][col = wn*64+16j+m16]  (C/D: col=lane&15, row=4*(lane>>4)+reg)
  float wfv[4][4];  // [t][j]
#pragma unroll
  for (int t = 0; t < 4; ++t)
#pragma unroll
    for (int j = 0; j < 4; ++j)
      wfv[t][j] = Wf[t * H_ + hbase + wn * 64 + j * 16 + m16];
  float bias[4];
#pragma unroll
  for (int j = 0; j < 4; ++j) bias[j] = be[n0 + wn * 64 + j * 16 + m16];

  const int reg_sel = m16 >> 2, t_sel = m16 & 3;  // slot this lane owns after reduce
#pragma unroll
  for (int i = 0; i < 4; ++i) {
    float eo[4][4];  // [j][reg]
#pragma unroll
    for (int j = 0; j < 4; ++j)
#pragma unroll
      for (int r = 0; r < 4; ++r) eo[j][r] = fmaxf(acc[i][j][r] + bias[j], 0.f);
    float p[16];  // [reg*4 + t] partial over this lane's 4 cols
#pragma unroll
    for (int r = 0; r < 4; ++r)
#pragma unroll
      for (int t = 0; t < 4; ++t) {
        float v = 0.f;
#pragma unroll
        for (int j = 0; j < 4; ++j) v += eo[j][r] * wfv[t][j];
        p[r * 4 + t] = v;
      }
    // butterfly-sum over the 16 m16-lanes (same q => same rows, disjoint cols)
#pragma unroll
    for (int mask = 1; mask < 16; mask <<= 1)
#pragma unroll
      for (int s = 0; s < 16; ++s) p[s] += __shfl_xor(p[s], mask, 64);
    // lane keeps slot s = m16
    float v = p[0];
#pragma unroll
    for (int s = 1; s < 16; ++s) v = (m16 == s) ? p[s] : v;
    int row = wm * 64 + i * 16 + q * 4 + reg_sel;
    allsums[wn * 512 + row * 4 + t_sel] = v;
  }
  __syncthreads();

  // combine wn-halves, apply gate, emit per-tile partial (deterministic)
  const int e_idx = (int)(n0 >> 9);
#pragma unroll
  for (int oi = 0; oi < 2; ++oi) {
    int o = tid * 2 + oi;  // 512 = 128 rows x 4 t
    int row = o >> 2, t = o & 3;
    float s = allsums[row * 4 + t] + allsums[512 + row * 4 + t];
    size_t b = m0 + row;
    float gv = g[b * 64 + t * 16 + e_idx];
    partials[(size_t)nb * (T_ * B_) + (size_t)t * B_ + b] = gv * s;
  }
}

// out[t,b] = bf[t] + sum_nb partials[nb][t][b]
__global__ __launch_bounds__(256) void reduce_kernel(const float* __restrict__ partials,
                                                     const float* __restrict__ bfv,
                                                     float* __restrict__ out) {
  int i = blockIdx.x * 256 + threadIdx.x;  // T_*B_ = 32768
  float s = bfv[i >> 13];
#pragma unroll 4
  for (int nb = 0; nb < 64; ++nb) s += partials[(size_t)nb * (T_ * B_) + i];
  out[i] = s;
}

extern "C" void kernel_launch(void* const* d_in, const int* in_sizes, int n_in,
                              void* d_out, int out_size, void* d_ws, size_t ws_size,
                              hipStream_t stream) {
  const float* x = (const float*)d_in[0];   // [B, I]
  const float* We = (const float*)d_in[1];  // [E, H, I]
  const float* be = (const float*)d_in[2];  // [E, H]
  const float* Wg = (const float*)d_in[3];  // [T, E, I]
  const float* bg = (const float*)d_in[4];  // [T, E]
  const float* Wf = (const float*)d_in[5];  // [T, H]
  const float* bf = (const float*)d_in[6];  // [T]
  float* out = (float*)d_out;               // [T, B, 1]

  // ws: xb (16.8MB) | wb (16.8MB) | g (2.1MB) | partials (8.4MB) ~ 44MB
  unsigned short* xb = (unsigned short*)d_ws;
  unsigned short* wb = xb + (size_t)B_ * K_;
  float* g = (float*)(wb + (size_t)N_ * K_);
  float* partials = g + (size_t)B_ * 64;

  cvt_bf16_kernel<<<(N_ * K_ / 4 + 255) / 256, 256, 0, stream>>>(We, wb, N_ * K_ / 4);
  gates_kernel<<<B_ / 16, 256, 0, stream>>>(x, Wg, bg, g, xb);
  dim3 grid(N_ / 128, B_ / 128);
  moe_main_kernel<<<grid, 256, 0, stream>>>(xb, wb, be, Wf, g, partials);
  reduce_kernel<<<(T_ * B_) / 256, 256, 0, stream>>>(partials, bf, out);
}

// Round 6
// 315.170 us; speedup vs baseline: 1.7363x; 1.1537x over previous
//
#include <hip/hip_runtime.h>
#include <hip/hip_bf16.h>
#include <stdint.h>

// MMoE: E=16 experts, T=4 tasks, H=512, I=1024, B=8192.
// out[t,b] = sum_e g[b,t,e] * (sum_h relu(x@We^T+be)[b,e,h] * Wf[t,h]) + bf[t]
// R5 finding: total 363.6 µs but main GEMM only 201.7 µs -> ~160 µs hidden in
// gates_kernel's uncoalesced Wg reads (64 cache lines per wave-load, ~2.1 GB L2).
// R6: blocked-transpose repack of Wg (Wt[i4][te][4]) -> gates reads coalesced.
// Main kernel unchanged (680 TF effective, passed at absmax 1.95e-3).

#define E_ 16
#define T_ 4
#define H_ 512
#define I_ 1024
#define B_ 8192
#define N_ (E_ * H_) /* 8192 */
#define K_ I_        /* 1024 */

typedef __bf16 bf16x8 __attribute__((ext_vector_type(8)));
typedef float f32x4 __attribute__((ext_vector_type(4)));

__device__ __forceinline__ unsigned short f2bf_rne(float f) {
  unsigned int b = __float_as_uint(f);
  b += 0x7fffu + ((b >> 16) & 1u);
  return (unsigned short)(b >> 16);
}

// fp32 -> bf16 (RNE), float4 in / ushort4 out per thread
__global__ __launch_bounds__(256) void cvt_bf16_kernel(const float* __restrict__ in,
                                                       unsigned short* __restrict__ out,
                                                       int n4) {
  int i = blockIdx.x * 256 + threadIdx.x;
  if (i >= n4) return;
  float4 v = reinterpret_cast<const float4*>(in)[i];
  ushort4 o;
  o.x = f2bf_rne(v.x);
  o.y = f2bf_rne(v.y);
  o.z = f2bf_rne(v.z);
  o.w = f2bf_rne(v.w);
  reinterpret_cast<ushort4*>(out)[i] = o;
}

// Wg[te][i] (te = t*16+e in [0,64), i in [0,1024)) -> Wt[i4][te][ii], i=i4*4+ii.
// 65536 elements; makes gates' Wg reads lane-coalesced (float4 per (i4,te)).
__global__ __launch_bounds__(256) void repack_wg_kernel(const float* __restrict__ Wg,
                                                        float* __restrict__ Wt) {
  int o = blockIdx.x * 256 + threadIdx.x;  // 64*1024 = 65536
  int ii = o & 3, te = (o >> 2) & 63, i4 = o >> 8;
  Wt[o] = Wg[te * I_ + i4 * 4 + ii];
}

// gates: g[b,t,e] = softmax_e( x[b,:]@Wg[t,e,:] + bg[t,e] ), fp32.
// Wt blocked-transposed -> lane te reads wt4[i4*64+te]: coalesced 1KB/wave.
// Also emits x converted to bf16 (x tile already staged in LDS -> free read).
__global__ __launch_bounds__(256) void gates_kernel(const float* __restrict__ x,
                                                    const float* __restrict__ Wt,
                                                    const float* __restrict__ bg,
                                                    float* __restrict__ g,
                                                    unsigned short* __restrict__ xb) {
  __shared__ float xs[16 * I_];  // 64 KB
  const int tid = threadIdx.x;
  const int b0 = blockIdx.x * 16;
  const float4* xg = reinterpret_cast<const float4*>(x + (size_t)b0 * I_);
  float4* xs4 = reinterpret_cast<float4*>(xs);
#pragma unroll
  for (int it = 0; it < 16; ++it) xs4[tid + 256 * it] = xg[tid + 256 * it];
  __syncthreads();

  // fused x -> bf16 conversion (16 float4 per thread)
  ushort4* xb4 = reinterpret_cast<ushort4*>(xb + (size_t)b0 * I_);
#pragma unroll
  for (int it = 0; it < 16; ++it) {
    float4 v = xs4[tid + 256 * it];
    ushort4 o;
    o.x = f2bf_rne(v.x);
    o.y = f2bf_rne(v.y);
    o.z = f2bf_rne(v.z);
    o.w = f2bf_rne(v.w);
    xb4[tid + 256 * it] = o;
  }

  const int te = tid & 63;    // t = te>>4, e = te&15
  const int bgrp = tid >> 6;  // wave id -> which 4 b-rows
  const float4* wt4 = reinterpret_cast<const float4*>(Wt);  // [i4][te] float4
  float acc[4] = {0.f, 0.f, 0.f, 0.f};
  for (int i4 = 0; i4 < I_ / 4; ++i4) {
    float4 wv = wt4[i4 * 64 + te];  // consecutive lanes -> consecutive float4s
#pragma unroll
    for (int bl = 0; bl < 4; ++bl) {
      float4 xv = xs4[(bgrp * 4 + bl) * (I_ / 4) + i4];  // wave-uniform: LDS broadcast
      acc[bl] += wv.x * xv.x + wv.y * xv.y + wv.z * xv.z + wv.w * xv.w;
    }
  }
  float bgv = bg[te];
#pragma unroll
  for (int bl = 0; bl < 4; ++bl) {
    float logit = acc[bl] + bgv;
    float m = logit;
#pragma unroll
    for (int mask = 1; mask < 16; mask <<= 1) m = fmaxf(m, __shfl_xor(m, mask, 64));
    float ex = __expf(logit - m);
    float s = ex;
#pragma unroll
    for (int mask = 1; mask < 16; mask <<= 1) s += __shfl_xor(s, mask, 64);
    int b = b0 + bgrp * 4 + bl;
    g[(size_t)b * 64 + te] = ex / s;
  }
}

__device__ __forceinline__ void gld_lds16(const void* gp, void* lp) {
  __builtin_amdgcn_global_load_lds((const __attribute__((address_space(1))) void*)gp,
                                   (__attribute__((address_space(3))) void*)lp, 16, 0, 0);
}

// Main: bf16 GEMM C = A x B^T (fp32 acc), relu+bias, Wf-contraction + gating
// in registers (shfl butterfly over the 16 m16-lanes), per-tile partial to
// global partials[nb][t][b] (deterministic; no atomics).
// m97 structure: 128x128 tile, BK=32, 4 waves x 4x4 of 16x16x32 MFMA,
// global_load_lds width=16 staging, XOR chunk swizzle for ds_read_b128.
__global__ __launch_bounds__(256, 2) void moe_main_kernel(
    const unsigned short* __restrict__ A,   // x bf16 [B_][K_]
    const unsigned short* __restrict__ Bm,  // We bf16 [N_][K_]
    const float* __restrict__ be,           // [E_*H_] flat == indexed by n
    const float* __restrict__ Wf,           // [T_][H_]
    const float* __restrict__ g,            // [B_][64] (t*16+e)
    float* __restrict__ partials)           // [64 nb][T_][B_]
{
  __shared__ struct {
    unsigned short A[128 * 32];
    unsigned short B[128 * 32];
  } st;                               // 16 KB staging
  __shared__ float allsums[2 * 512];  // [wn][row*4+t], 4 KB

  const int tid = threadIdx.x;
  const int w = tid >> 6, l = tid & 63;
  const int wm = w >> 1, wn = w & 1;
  const int m16 = l & 15, q = l >> 4;
  const int nb = blockIdx.x, mb = blockIdx.y;
  const size_t m0 = (size_t)mb * 128, n0 = (size_t)nb * 128;

  // staging: LDS row-major [128][4 chunks of 16B]; chunk c of row r at slot c^((r>>1)&3)
  const int r0s = (w * 2 + 0) * 16 + (l >> 2);
  const int r1s = (w * 2 + 1) * 16 + (l >> 2);
  const int slot = l & 3;
  const int c0 = slot ^ ((r0s >> 1) & 3);
  const int c1 = slot ^ ((r1s >> 1) & 3);
  const size_t offA0 = (m0 + r0s) * K_ + c0 * 8;
  const size_t offA1 = (m0 + r1s) * K_ + c1 * 8;
  const size_t offB0 = (n0 + r0s) * K_ + c0 * 8;
  const size_t offB1 = (n0 + r1s) * K_ + c1 * 8;
  const int l0 = (w * 2 + 0) * 512;  // wave-uniform LDS base (HW adds lane*16)
  const int l1 = (w * 2 + 1) * 512;

  const int arow = wm * 64 + m16;
  const int brow = wn * 64 + m16;
  const int sA = q ^ ((arow >> 1) & 3);  // constant over i: (i*16)>>1 ≡ 0 mod 4
  const int sB = q ^ ((brow >> 1) & 3);

  f32x4 acc[4][4] = {};

  for (int k0 = 0; k0 < K_; k0 += 32) {
    __syncthreads();
    gld_lds16(A + offA0 + k0, st.A + l0);
    gld_lds16(A + offA1 + k0, st.A + l1);
    gld_lds16(Bm + offB0 + k0, st.B + l0);
    gld_lds16(Bm + offB1 + k0, st.B + l1);
    __syncthreads();  // vmcnt(0) drain before barrier
    bf16x8 af[4], bfr[4];
#pragma unroll
    for (int i = 0; i < 4; ++i)
      af[i] = *reinterpret_cast<const bf16x8*>(st.A + (arow + i * 16) * 32 + sA * 8);
#pragma unroll
    for (int j = 0; j < 4; ++j)
      bfr[j] = *reinterpret_cast<const bf16x8*>(st.B + (brow + j * 16) * 32 + sB * 8);
#pragma unroll
    for (int i = 0; i < 4; ++i)
#pragma unroll
      for (int j = 0; j < 4; ++j)
        acc[i][j] = __builtin_amdgcn_mfma_f32_16x16x32_bf16(af[i], bfr[j], acc[i][j], 0, 0, 0);
  }

  __syncthreads();

  const int hbase = (int)(n0 & 511);  // h-offset of this tile (expert = n0>>9)

  // Per-lane epilogue: lane's acc element (i,j,reg) is
  // D[row = wm*64+16i+4q+reg][col = wn*64+16j+m16]  (C/D: col=lane&15, row=4*(lane>>4)+reg)
  float wfv[4][4];  // [t][j]
#pragma unroll
  for (int t = 0; t < 4; ++t)
#pragma unroll
    for (int j = 0; j < 4; ++j)
      wfv[t][j] = Wf[t * H_ + hbase + wn * 64 + j * 16 + m16];
  float bias[4];
#pragma unroll
  for (int j = 0; j < 4; ++j) bias[j] = be[n0 + wn * 64 + j * 16 + m16];

  const int reg_sel = m16 >> 2, t_sel = m16 & 3;  // slot this lane owns after reduce
#pragma unroll
  for (int i = 0; i < 4; ++i) {
    float eo[4][4];  // [j][reg]
#pragma unroll
    for (int j = 0; j < 4; ++j)
#pragma unroll
      for (int r = 0; r < 4; ++r) eo[j][r] = fmaxf(acc[i][j][r] + bias[j], 0.f);
    float p[16];  // [reg*4 + t] partial over this lane's 4 cols
#pragma unroll
    for (int r = 0; r < 4; ++r)
#pragma unroll
      for (int t = 0; t < 4; ++t) {
        float v = 0.f;
#pragma unroll
        for (int j = 0; j < 4; ++j) v += eo[j][r] * wfv[t][j];
        p[r * 4 + t] = v;
      }
    // butterfly-sum over the 16 m16-lanes (same q => same rows, disjoint cols)
#pragma unroll
    for (int mask = 1; mask < 16; mask <<= 1)
#pragma unroll
      for (int s = 0; s < 16; ++s) p[s] += __shfl_xor(p[s], mask, 64);
    // lane keeps slot s = m16
    float v = p[0];
#pragma unroll
    for (int s = 1; s < 16; ++s) v = (m16 == s) ? p[s] : v;
    int row = wm * 64 + i * 16 + q * 4 + reg_sel;
    allsums[wn * 512 + row * 4 + t_sel] = v;
  }
  __syncthreads();

  // combine wn-halves, apply gate, emit per-tile partial (deterministic)
  const int e_idx = (int)(n0 >> 9);
#pragma unroll
  for (int oi = 0; oi < 2; ++oi) {
    int o = tid * 2 + oi;  // 512 = 128 rows x 4 t
    int row = o >> 2, t = o & 3;
    float s = allsums[row * 4 + t] + allsums[512 + row * 4 + t];
    size_t b = m0 + row;
    float gv = g[b * 64 + t * 16 + e_idx];
    partials[(size_t)nb * (T_ * B_) + (size_t)t * B_ + b] = gv * s;
  }
}

// out[t,b] = bf[t] + sum_nb partials[nb][t][b]
__global__ __launch_bounds__(128) void reduce_kernel(const float* __restrict__ partials,
                                                     const float* __restrict__ bfv,
                                                     float* __restrict__ out) {
  int i = blockIdx.x * 128 + threadIdx.x;  // T_*B_ = 32768
  float s = bfv[i >> 13];
#pragma unroll 4
  for (int nb = 0; nb < 64; ++nb) s += partials[(size_t)nb * (T_ * B_) + i];
  out[i] = s;
}

extern "C" void kernel_launch(void* const* d_in, const int* in_sizes, int n_in,
                              void* d_out, int out_size, void* d_ws, size_t ws_size,
                              hipStream_t stream) {
  const float* x = (const float*)d_in[0];   // [B, I]
  const float* We = (const float*)d_in[1];  // [E, H, I]
  const float* be = (const float*)d_in[2];  // [E, H]
  const float* Wg = (const float*)d_in[3];  // [T, E, I]
  const float* bg = (const float*)d_in[4];  // [T, E]
  const float* Wf = (const float*)d_in[5];  // [T, H]
  const float* bf = (const float*)d_in[6];  // [T]
  float* out = (float*)d_out;               // [T, B, 1]

  // ws: xb (16.8MB) | wb (16.8MB) | g (2.1MB) | partials (8.4MB) | Wt (0.26MB)
  unsigned short* xb = (unsigned short*)d_ws;
  unsigned short* wb = xb + (size_t)B_ * K_;
  float* g = (float*)(wb + (size_t)N_ * K_);
  float* partials = g + (size_t)B_ * 64;
  float* Wt = partials + (size_t)64 * T_ * B_;

  cvt_bf16_kernel<<<(N_ * K_ / 4 + 255) / 256, 256, 0, stream>>>(We, wb, N_ * K_ / 4);
  repack_wg_kernel<<<(64 * I_) / 256, 256, 0, stream>>>(Wg, Wt);
  gates_kernel<<<B_ / 16, 256, 0, stream>>>(x, Wt, bg, g, xb);
  dim3 grid(N_ / 128, B_ / 128);
  moe_main_kernel<<<grid, 256, 0, stream>>>(xb, wb, be, Wf, g, partials);
  reduce_kernel<<<(T_ * B_) / 128, 128, 0, stream>>>(partials, bf, out);
}

// Round 7
// 306.931 us; speedup vs baseline: 1.7829x; 1.0268x over previous
//
#include <hip/hip_runtime.h>
#include <hip/hip_bf16.h>
#include <stdint.h>

// MMoE: E=16 experts, T=4 tasks, H=512, I=1024, B=8192.
// out[t,b] = sum_e g[b,t,e] * (sum_h relu(x@We^T+be)[b,e,h] * Wf[t,h]) + bf[t]
// R6 finding: non-main time still ~115 µs; gates' scalar-FMA structure is
// LDS-pipe-bound (~2.1M ds_read_b128). R7: gates -> MFMA logits GEMM
// [8192x1024]x[64x1024]^T bf16 + in-register 16-lane-butterfly softmax;
// one merged cvt kernel for x/We/Wg. Main GEMM + reduce unchanged.

#define E_ 16
#define T_ 4
#define H_ 512
#define I_ 1024
#define B_ 8192
#define N_ (E_ * H_) /* 8192 */
#define K_ I_        /* 1024 */

typedef __bf16 bf16x8 __attribute__((ext_vector_type(8)));
typedef float f32x4 __attribute__((ext_vector_type(4)));

__device__ __forceinline__ unsigned short f2bf_rne(float f) {
  unsigned int b = __float_as_uint(f);
  b += 0x7fffu + ((b >> 16) & 1u);
  return (unsigned short)(b >> 16);
}

#define N4X (B_ * K_ / 4) /* 2097152 */
#define N4W (N_ * K_ / 4) /* 2097152 */
#define N4G (64 * K_ / 4) /* 16384 */

// merged fp32 -> bf16 (RNE) for x | We | Wg, float4 in / ushort4 out
__global__ __launch_bounds__(256) void cvt3_kernel(const float* __restrict__ x,
                                                   const float* __restrict__ We,
                                                   const float* __restrict__ Wg,
                                                   unsigned short* __restrict__ xb,
                                                   unsigned short* __restrict__ wb,
                                                   unsigned short* __restrict__ wgb) {
  int i = blockIdx.x * 256 + threadIdx.x;
  const float* src;
  unsigned short* dst;
  int j;
  if (i < N4X) {
    src = x; dst = xb; j = i;
  } else if (i < N4X + N4W) {
    src = We; dst = wb; j = i - N4X;
  } else if (i < N4X + N4W + N4G) {
    src = Wg; dst = wgb; j = i - (N4X + N4W);
  } else {
    return;
  }
  float4 v = reinterpret_cast<const float4*>(src)[j];
  ushort4 o;
  o.x = f2bf_rne(v.x);
  o.y = f2bf_rne(v.y);
  o.z = f2bf_rne(v.z);
  o.w = f2bf_rne(v.w);
  reinterpret_cast<ushort4*>(dst)[j] = o;
}

__device__ __forceinline__ void gld_lds16(const void* gp, void* lp) {
  __builtin_amdgcn_global_load_lds((const __attribute__((address_space(1))) void*)gp,
                                   (__attribute__((address_space(3))) void*)lp, 16, 0, 0);
}

// logits L[b][te] = x[b,:]@Wg[te,:] + bg[te] via bf16 MFMA (Wg [T][E][I] is
// already B^T [64][1024]), then softmax over e (= the 16 m16-lanes) in
// registers -> g[b][64]. Tile: M=128, N=64, BK=32; 4 waves x 32 rows each.
__global__ __launch_bounds__(256) void logits_softmax_kernel(
    const unsigned short* __restrict__ A,    // x bf16 [B_][K_]
    const unsigned short* __restrict__ Bm,   // Wg bf16 [64][K_]
    const float* __restrict__ bg,            // [64]
    float* __restrict__ g)                   // [B_][64]
{
  __shared__ struct {
    unsigned short A[128 * 32];  // 8 KB
    unsigned short B[64 * 32];   // 4 KB
  } st;

  const int tid = threadIdx.x;
  const int w = tid >> 6, l = tid & 63;
  const int m16 = l & 15, q = l >> 4;
  const size_t m0 = (size_t)blockIdx.x * 128;

  // A staging: rows w*32..w*32+31, 2 chunks/thread (as in main kernel)
  const int r0s = (w * 2 + 0) * 16 + (l >> 2);
  const int r1s = (w * 2 + 1) * 16 + (l >> 2);
  const int slot = l & 3;
  const int c0 = slot ^ ((r0s >> 1) & 3);
  const int c1 = slot ^ ((r1s >> 1) & 3);
  const size_t offA0 = (m0 + r0s) * K_ + c0 * 8;
  const size_t offA1 = (m0 + r1s) * K_ + c1 * 8;
  const int l0 = (w * 2 + 0) * 512;
  const int l1 = (w * 2 + 1) * 512;
  // B staging: 64 rows, 1 chunk/thread; wave w covers rows w*16..w*16+15
  const int rBs = w * 16 + (l >> 2);
  const int cB = slot ^ ((rBs >> 1) & 3);
  const size_t offB = (size_t)rBs * K_ + cB * 8;
  const int lB = w * 512;

  const int arow = w * 32 + m16;
  const int sA = q ^ ((arow >> 1) & 3);  // (i*16>>1)&3 == 0 -> same for both i
  const int sB = q ^ ((m16 >> 1) & 3);   // brow = j*16+m16, j*16 drops out

  f32x4 acc[2][4] = {};

  for (int k0 = 0; k0 < K_; k0 += 32) {
    __syncthreads();
    gld_lds16(A + offA0 + k0, st.A + l0);
    gld_lds16(A + offA1 + k0, st.A + l1);
    gld_lds16(Bm + offB + k0, st.B + lB);
    __syncthreads();
    bf16x8 af[2], bfr[4];
#pragma unroll
    for (int i = 0; i < 2; ++i)
      af[i] = *reinterpret_cast<const bf16x8*>(st.A + (arow + i * 16) * 32 + sA * 8);
#pragma unroll
    for (int j = 0; j < 4; ++j)
      bfr[j] = *reinterpret_cast<const bf16x8*>(st.B + (j * 16 + m16) * 32 + sB * 8);
#pragma unroll
    for (int i = 0; i < 2; ++i)
#pragma unroll
      for (int j = 0; j < 4; ++j)
        acc[i][j] = __builtin_amdgcn_mfma_f32_16x16x32_bf16(af[i], bfr[j], acc[i][j], 0, 0, 0);
  }

  // acc[i][j][r] = L[row = w*32+16i+4q+r][te = j*16+m16]; t = j, e = m16.
  float bgv[4];
#pragma unroll
  for (int j = 0; j < 4; ++j) bgv[j] = bg[j * 16 + m16];

#pragma unroll
  for (int i = 0; i < 2; ++i) {
    float lg[4][4];  // [r][j]
#pragma unroll
    for (int j = 0; j < 4; ++j)
#pragma unroll
      for (int r = 0; r < 4; ++r) lg[r][j] = acc[i][j][r] + bgv[j];
#pragma unroll
    for (int r = 0; r < 4; ++r) {
#pragma unroll
      for (int j = 0; j < 4; ++j) {
        float m = lg[r][j];
#pragma unroll
        for (int mask = 1; mask < 16; mask <<= 1) m = fmaxf(m, __shfl_xor(m, mask, 64));
        float ex = __expf(lg[r][j] - m);
        float s = ex;
#pragma unroll
        for (int mask = 1; mask < 16; mask <<= 1) s += __shfl_xor(s, mask, 64);
        size_t b = m0 + w * 32 + i * 16 + q * 4 + r;
        g[b * 64 + j * 16 + m16] = ex / s;
      }
    }
  }
}

// Main: bf16 GEMM C = A x B^T (fp32 acc), relu+bias, Wf-contraction + gating
// in registers (shfl butterfly over the 16 m16-lanes), per-tile partial to
// global partials[nb][t][b] (deterministic; no atomics).
// m97 structure: 128x128 tile, BK=32, 4 waves x 4x4 of 16x16x32 MFMA,
// global_load_lds width=16 staging, XOR chunk swizzle for ds_read_b128.
__global__ __launch_bounds__(256, 2) void moe_main_kernel(
    const unsigned short* __restrict__ A,   // x bf16 [B_][K_]
    const unsigned short* __restrict__ Bm,  // We bf16 [N_][K_]
    const float* __restrict__ be,           // [E_*H_] flat == indexed by n
    const float* __restrict__ Wf,           // [T_][H_]
    const float* __restrict__ g,            // [B_][64] (t*16+e)
    float* __restrict__ partials)           // [64 nb][T_][B_]
{
  __shared__ struct {
    unsigned short A[128 * 32];
    unsigned short B[128 * 32];
  } st;                               // 16 KB staging
  __shared__ float allsums[2 * 512];  // [wn][row*4+t], 4 KB

  const int tid = threadIdx.x;
  const int w = tid >> 6, l = tid & 63;
  const int wm = w >> 1, wn = w & 1;
  const int m16 = l & 15, q = l >> 4;
  const int nb = blockIdx.x, mb = blockIdx.y;
  const size_t m0 = (size_t)mb * 128, n0 = (size_t)nb * 128;

  // staging: LDS row-major [128][4 chunks of 16B]; chunk c of row r at slot c^((r>>1)&3)
  const int r0s = (w * 2 + 0) * 16 + (l >> 2);
  const int r1s = (w * 2 + 1) * 16 + (l >> 2);
  const int slot = l & 3;
  const int c0 = slot ^ ((r0s >> 1) & 3);
  const int c1 = slot ^ ((r1s >> 1) & 3);
  const size_t offA0 = (m0 + r0s) * K_ + c0 * 8;
  const size_t offA1 = (m0 + r1s) * K_ + c1 * 8;
  const size_t offB0 = (n0 + r0s) * K_ + c0 * 8;
  const size_t offB1 = (n0 + r1s) * K_ + c1 * 8;
  const int l0 = (w * 2 + 0) * 512;  // wave-uniform LDS base (HW adds lane*16)
  const int l1 = (w * 2 + 1) * 512;

  const int arow = wm * 64 + m16;
  const int brow = wn * 64 + m16;
  const int sA = q ^ ((arow >> 1) & 3);  // constant over i: (i*16)>>1 ≡ 0 mod 4
  const int sB = q ^ ((brow >> 1) & 3);

  f32x4 acc[4][4] = {};

  for (int k0 = 0; k0 < K_; k0 += 32) {
    __syncthreads();
    gld_lds16(A + offA0 + k0, st.A + l0);
    gld_lds16(A + offA1 + k0, st.A + l1);
    gld_lds16(Bm + offB0 + k0, st.B + l0);
    gld_lds16(Bm + offB1 + k0, st.B + l1);
    __syncthreads();  // vmcnt(0) drain before barrier
    bf16x8 af[4], bfr[4];
#pragma unroll
    for (int i = 0; i < 4; ++i)
      af[i] = *reinterpret_cast<const bf16x8*>(st.A + (arow + i * 16) * 32 + sA * 8);
#pragma unroll
    for (int j = 0; j < 4; ++j)
      bfr[j] = *reinterpret_cast<const bf16x8*>(st.B + (brow + j * 16) * 32 + sB * 8);
#pragma unroll
    for (int i = 0; i < 4; ++i)
#pragma unroll
      for (int j = 0; j < 4; ++j)
        acc[i][j] = __builtin_amdgcn_mfma_f32_16x16x32_bf16(af[i], bfr[j], acc[i][j], 0, 0, 0);
  }

  __syncthreads();

  const int hbase = (int)(n0 & 511);  // h-offset of this tile (expert = n0>>9)

  // Per-lane epilogue: lane's acc element (i,j,reg) is
  // D[row = wm*64+16i+4q+reg][col = wn*64+16j+m16]  (C/D: col=lane&15, row=4*(lane>>4)+reg)
  float wfv[4][4];  // [t][j]
#pragma unroll
  for (int t = 0; t < 4; ++t)
#pragma unroll
    for (int j = 0; j < 4; ++j)
      wfv[t][j] = Wf[t * H_ + hbase + wn * 64 + j * 16 + m16];
  float bias[4];
#pragma unroll
  for (int j = 0; j < 4; ++j) bias[j] = be[n0 + wn * 64 + j * 16 + m16];

  const int reg_sel = m16 >> 2, t_sel = m16 & 3;  // slot this lane owns after reduce
#pragma unroll
  for (int i = 0; i < 4; ++i) {
    float eo[4][4];  // [j][reg]
#pragma unroll
    for (int j = 0; j < 4; ++j)
#pragma unroll
      for (int r = 0; r < 4; ++r) eo[j][r] = fmaxf(acc[i][j][r] + bias[j], 0.f);
    float p[16];  // [reg*4 + t] partial over this lane's 4 cols
#pragma unroll
    for (int r = 0; r < 4; ++r)
#pragma unroll
      for (int t = 0; t < 4; ++t) {
        float v = 0.f;
#pragma unroll
        for (int j = 0; j < 4; ++j) v += eo[j][r] * wfv[t][j];
        p[r * 4 + t] = v;
      }
    // butterfly-sum over the 16 m16-lanes (same q => same rows, disjoint cols)
#pragma unroll
    for (int mask = 1; mask < 16; mask <<= 1)
#pragma unroll
      for (int s = 0; s < 16; ++s) p[s] += __shfl_xor(p[s], mask, 64);
    // lane keeps slot s = m16
    float v = p[0];
#pragma unroll
    for (int s = 1; s < 16; ++s) v = (m16 == s) ? p[s] : v;
    int row = wm * 64 + i * 16 + q * 4 + reg_sel;
    allsums[wn * 512 + row * 4 + t_sel] = v;
  }
  __syncthreads();

  // combine wn-halves, apply gate, emit per-tile partial (deterministic)
  const int e_idx = (int)(n0 >> 9);
#pragma unroll
  for (int oi = 0; oi < 2; ++oi) {
    int o = tid * 2 + oi;  // 512 = 128 rows x 4 t
    int row = o >> 2, t = o & 3;
    float s = allsums[row * 4 + t] + allsums[512 + row * 4 + t];
    size_t b = m0 + row;
    float gv = g[b * 64 + t * 16 + e_idx];
    partials[(size_t)nb * (T_ * B_) + (size_t)t * B_ + b] = gv * s;
  }
}

// out[t,b] = bf[t] + sum_nb partials[nb][t][b]
__global__ __launch_bounds__(128) void reduce_kernel(const float* __restrict__ partials,
                                                     const float* __restrict__ bfv,
                                                     float* __restrict__ out) {
  int i = blockIdx.x * 128 + threadIdx.x;  // T_*B_ = 32768
  float s = bfv[i >> 13];
#pragma unroll 4
  for (int nb = 0; nb < 64; ++nb) s += partials[(size_t)nb * (T_ * B_) + i];
  out[i] = s;
}

extern "C" void kernel_launch(void* const* d_in, const int* in_sizes, int n_in,
                              void* d_out, int out_size, void* d_ws, size_t ws_size,
                              hipStream_t stream) {
  const float* x = (const float*)d_in[0];   // [B, I]
  const float* We = (const float*)d_in[1];  // [E, H, I]
  const float* be = (const float*)d_in[2];  // [E, H]
  const float* Wg = (const float*)d_in[3];  // [T, E, I]
  const float* bg = (const float*)d_in[4];  // [T, E]
  const float* Wf = (const float*)d_in[5];  // [T, H]
  const float* bf = (const float*)d_in[6];  // [T]
  float* out = (float*)d_out;               // [T, B, 1]

  // ws: xb (16.8MB) | wb (16.8MB) | wgb (0.13MB) | g (2.1MB) | partials (8.4MB)
  unsigned short* xb = (unsigned short*)d_ws;
  unsigned short* wb = xb + (size_t)B_ * K_;
  unsigned short* wgb = wb + (size_t)N_ * K_;
  float* g = (float*)(wgb + (size_t)64 * K_);
  float* partials = g + (size_t)B_ * 64;

  cvt3_kernel<<<(N4X + N4W + N4G + 255) / 256, 256, 0, stream>>>(x, We, Wg, xb, wb, wgb);
  logits_softmax_kernel<<<B_ / 128, 256, 0, stream>>>(xb, wgb, bg, g);
  dim3 grid(N_ / 128, B_ / 128);
  moe_main_kernel<<<grid, 256, 0, stream>>>(xb, wb, be, Wf, g, partials);
  reduce_kernel<<<(T_ * B_) / 128, 128, 0, stream>>>(partials, bf, out);
}